// Round 9
// baseline (1201.808 us; speedup 1.0000x reference)
//
#include <hip/hip_runtime.h>

// GCN forward: 4x [GEMM -> symmetric-normalized aggregation -> lrelu -> BN(folded)]
// then mean-pool per graph @ Wout.
//
// Key structure:
//  - CSR via counting sort, rank captured in count pass (atomicAdd return) ->
//    placement pass has NO atomics.
//  - Layer 1 commuted: A(x@W0) = (Ax)@W0; u bf16 24B rows (slot 9 = bf16(dinv) so
//    spmm9's lane 9 computes sd -> q for free).
//  - dinv folded into GEMM/gather epilogues; BN folded into next GEMM.
//  - k_spmm gather wall (R2-R8): per-edge ~43 cy fixed + ~14.5 cy/128B line,
//    bound by chip-level random-line service (~17-25 G lines/s); ILP/nt-load/
//    precision probes all converge. This round: 1 node/32-lane group (8/block).
//  - cntG computed by binary search inside k_out (sorted batch).
//  - L bf16 (256B rows), Abuf bf16; 128x128 GEMMs on bf16 MFMA 16x16x32.
//  - Final layer fuses pool; per-block run-aggregated pacc atomics.

#define LRELU(z) ((z) > 0.f ? (z) : 0.01f * (z))
#define ADD4(d, s) \
  { d.x += s.x; d.y += s.y; d.z += s.z; d.w += s.w; }

typedef __attribute__((ext_vector_type(8))) short short8;
typedef __attribute__((ext_vector_type(4))) float float4v;

__device__ inline unsigned bf16_rn(float a) {
  unsigned u = __float_as_uint(a);
  return (u + 0x7FFFu + ((u >> 16) & 1u)) >> 16;
}

__device__ inline unsigned pack_bf16x2(float a, float b) {
  return bf16_rn(a) | (bf16_rn(b) << 16);
}

__device__ inline float bf16f(unsigned short s) {
  return __uint_as_float(((unsigned)s) << 16);
}

__device__ inline float4 unpack_bf16x4(uint2 u) {
  float4 r;
  r.x = __uint_as_float(u.x << 16);
  r.y = __uint_as_float(u.x & 0xffff0000u);
  r.z = __uint_as_float(u.y << 16);
  r.w = __uint_as_float(u.y & 0xffff0000u);
  return r;
}

// count pass: cnt[col]++ and record each edge's rank within its column.
__global__ __launch_bounds__(256) void k_count(const int* __restrict__ ei,
                                               int* __restrict__ cnt,
                                               int* __restrict__ rank, int E) {
  int i = blockIdx.x * 256 + threadIdx.x;
  if (i < E) rank[i] = atomicAdd(&cnt[ei[E + i]], 1);
}

// block-scan of cnt + dinv fused
__global__ __launch_bounds__(256) void k_scan1(const int* __restrict__ cnt,
                                               int* __restrict__ incl,
                                               int* __restrict__ bsums,
                                               float* __restrict__ dinv, int N) {
  __shared__ int s[256];
  int tid = threadIdx.x;
  int idx = blockIdx.x * 256 + tid;
  int v = (idx < N) ? cnt[idx] : 0;
  if (idx < N) dinv[idx] = rsqrtf((float)(v + 1));
  s[tid] = v;
  __syncthreads();
  for (int off = 1; off < 256; off <<= 1) {
    int t = (tid >= off) ? s[tid - off] : 0;
    __syncthreads();
    s[tid] += t;
    __syncthreads();
  }
  if (idx < N) incl[idx] = s[tid];
  if (tid == 255) bsums[blockIdx.x] = s[255];
}

// nb must be <= 512 (N <= 131072 here: nb = 391)
__global__ __launch_bounds__(512) void k_scan2(const int* __restrict__ bsums,
                                               int* __restrict__ bpref, int nb) {
  __shared__ int s[512];
  int tid = threadIdx.x;
  int v = (tid < nb) ? bsums[tid] : 0;
  s[tid] = v;
  __syncthreads();
  for (int off = 1; off < 512; off <<= 1) {
    int t = (tid >= off) ? s[tid - off] : 0;
    __syncthreads();
    s[tid] += t;
    __syncthreads();
  }
  bpref[tid] = s[tid] - v;  // exclusive prefix of block sums
}

// offs computation + u preparation fused: u[v][0:9] = bf16(x[v][0:9]*dinv[v]),
// slot 9 = bf16(dinv[v]), slots 10,11 = 0. 24B rows.
__global__ __launch_bounds__(256) void k_scan3_prep(
    const int* __restrict__ incl, const int* __restrict__ cnt,
    const int* __restrict__ bpref, int* __restrict__ offs,
    const float* __restrict__ x, const float* __restrict__ dinv,
    unsigned* __restrict__ u, int N) {
  int idx = blockIdx.x * 256 + threadIdx.x;
  if (idx >= N) return;
  offs[idx] = incl[idx] - cnt[idx] + bpref[blockIdx.x];
  float dv = dinv[idx];
  const float* xr = x + (size_t)idx * 9;
  unsigned p0 = pack_bf16x2(xr[0] * dv, xr[1] * dv);
  unsigned p1 = pack_bf16x2(xr[2] * dv, xr[3] * dv);
  unsigned p2 = pack_bf16x2(xr[4] * dv, xr[5] * dv);
  unsigned p3 = pack_bf16x2(xr[6] * dv, xr[7] * dv);
  unsigned p4 = pack_bf16x2(xr[8] * dv, dv);
  uint2* u2 = (uint2*)u;
  u2[(size_t)idx * 3 + 0] = make_uint2(p0, p1);
  u2[(size_t)idx * 3 + 1] = make_uint2(p2, p3);
  u2[(size_t)idx * 3 + 2] = make_uint2(p4, 0u);
}

// CSR placement: NO atomics (offs random read + rank from count pass).
__global__ __launch_bounds__(256) void k_csr(const int* __restrict__ ei,
                                             const int* __restrict__ offs,
                                             const int* __restrict__ rank,
                                             int* __restrict__ rows, int E) {
  int i = blockIdx.x * 256 + threadIdx.x;
  if (i < E) {
    int c = ei[E + i];
    rows[offs[c] + rank[i]] = ei[i];
  }
}

// ax[v] = dinv[v]*(u[v] + sum_in u[row]); lane 9 accumulates sum_in dinv[row]
// and emits q[v] = dinv*(dinv+sd). 16-lane group per node; coalesced 16-wide
// index load, shfl-broadcast, dependency-free 2B gathers (L2-resident source).
__global__ __launch_bounds__(256) void k_spmm9(
    const unsigned short* __restrict__ u, const int* __restrict__ offs,
    const int* __restrict__ cnt, const int* __restrict__ rows,
    const float* __restrict__ dinv, float* __restrict__ ax,
    float* __restrict__ q, int N) {
  const int t = threadIdx.x;
  const int g = t >> 4;
  const int f = t & 15;
  const int v = blockIdx.x * 16 + g;
  if (v >= N) return;
  const int st = offs[v];
  const int dg = cnt[v];
  const bool act = (f < 10);
  float a0 = (f < 9) ? bf16f(u[(size_t)v * 12 + f]) : 0.f;
  float a1 = 0.f, a2 = 0.f, a3 = 0.f;
  for (int b = 0; b < dg; b += 16) {
    int rem = dg - b;
    int idx = 0;
    if (f < rem) idx = rows[st + b + f];
    int mm = rem < 16 ? rem : 16;
    int e = 0;
    for (; e + 8 <= mm; e += 8) {
      int r0 = __shfl(idx, e + 0, 16), r1 = __shfl(idx, e + 1, 16);
      int r2 = __shfl(idx, e + 2, 16), r3 = __shfl(idx, e + 3, 16);
      int r4 = __shfl(idx, e + 4, 16), r5 = __shfl(idx, e + 5, 16);
      int r6 = __shfl(idx, e + 6, 16), r7 = __shfl(idx, e + 7, 16);
      float x0 = 0, x1 = 0, x2 = 0, x3 = 0, x4 = 0, x5 = 0, x6 = 0, x7 = 0;
      if (act) {
        x0 = bf16f(u[(size_t)r0 * 12 + f]); x1 = bf16f(u[(size_t)r1 * 12 + f]);
        x2 = bf16f(u[(size_t)r2 * 12 + f]); x3 = bf16f(u[(size_t)r3 * 12 + f]);
        x4 = bf16f(u[(size_t)r4 * 12 + f]); x5 = bf16f(u[(size_t)r5 * 12 + f]);
        x6 = bf16f(u[(size_t)r6 * 12 + f]); x7 = bf16f(u[(size_t)r7 * 12 + f]);
      }
      a0 += x0; a1 += x1; a2 += x2; a3 += x3;
      a0 += x4; a1 += x5; a2 += x6; a3 += x7;
    }
    for (; e + 4 <= mm; e += 4) {
      int r0 = __shfl(idx, e + 0, 16), r1 = __shfl(idx, e + 1, 16);
      int r2 = __shfl(idx, e + 2, 16), r3 = __shfl(idx, e + 3, 16);
      float x0 = 0, x1 = 0, x2 = 0, x3 = 0;
      if (act) {
        x0 = bf16f(u[(size_t)r0 * 12 + f]); x1 = bf16f(u[(size_t)r1 * 12 + f]);
        x2 = bf16f(u[(size_t)r2 * 12 + f]); x3 = bf16f(u[(size_t)r3 * 12 + f]);
      }
      a0 += x0; a1 += x1; a2 += x2; a3 += x3;
    }
    for (; e < mm; e++) {
      int r = __shfl(idx, e, 16);
      if (act) a0 += bf16f(u[(size_t)r * 12 + f]);
    }
  }
  float sum = (a0 + a1) + (a2 + a3);
  if (f < 9) {
    ax[(size_t)v * 12 + f] = sum * dinv[v];
  } else if (f == 9) {
    float dv = dinv[v];
    q[v] = dv * (dv + sum);
  }
}

// h1 = lrelu(ax[v][0:9] @ W0 + b0); writes Abuf (bf16); accumulates fp32 BN stats.
__global__ __launch_bounds__(256) void k_gemm_in(
    const float* __restrict__ ax, const float* __restrict__ W0,
    const float* __restrict__ b0, unsigned short* __restrict__ Abuf,
    float* __restrict__ stats, int N) {
  __shared__ float Wl[9 * 128];
  __shared__ float rs[128], rq[128];
  const int t = threadIdx.x;
  for (int i = t; i < 9 * 128; i += 256) Wl[i] = W0[i];
  if (t < 128) { rs[t] = 0.f; rq[t] = 0.f; }
  __syncthreads();
  const int col = t & 127;
  const int rsub = t >> 7;
  const int base = blockIdx.x * 16;
  const float bc = b0[col];
  float ls = 0.f, lq = 0.f;
  for (int it = 0; it < 8; it++) {
    int row = base + it * 2 + rsub;
    if (row < N) {
      const float* ar = ax + (size_t)row * 12;
      float acc = bc;
#pragma unroll
      for (int k = 0; k < 9; k++) acc += ar[k] * Wl[k * 128 + col];
      float a = LRELU(acc);
      Abuf[(size_t)row * 128 + col] = (unsigned short)bf16_rn(a);
      ls += a;
      lq += a * a;
    }
  }
  atomicAdd(&rs[col], ls);
  atomicAdd(&rq[col], lq);
  __syncthreads();
  if (t < 128) {
    atomicAdd(&stats[t], rs[t]);
    atomicAdd(&stats[128 + t], rq[t]);
  }
}

// bf16 MFMA GEMM: L[v][:] = bf16((A[v][:] @ Wf) * dinv[v]).
// Block: 64 rows, 4 waves x (16 rows x 128 cols). Wb pre-swizzled B-frag order.
__global__ __launch_bounds__(256) void k_gemm_mfma(
    const unsigned short* __restrict__ Ab, const uint4* __restrict__ Wb,
    const float* __restrict__ dinv, unsigned short* __restrict__ Lb, int N) {
  __shared__ uint4 Bl[2048];               // 32 KB: all B fragments
  __shared__ unsigned short Dl[4 * 2048];  // 16 KB: per-wave D staging
  __shared__ float dvs[64];
  const int t = threadIdx.x;
  const int row0 = blockIdx.x * 64;
#pragma unroll
  for (int i = 0; i < 8; i++) Bl[t + i * 256] = Wb[t + i * 256];
  if (t < 64) {
    int r = row0 + t;
    dvs[t] = (r < N) ? dinv[r] : 0.f;
  }
  __syncthreads();
  const int w = t >> 6;
  const int lane = t & 63;
  const int m = lane & 15;
  const int quad = lane >> 4;
  const int rowA = min(row0 + w * 16 + m, N - 1);
  const uint4* Arow = (const uint4*)(Ab + (size_t)rowA * 128);
  uint4 a[4];
#pragma unroll
  for (int kt = 0; kt < 4; kt++) a[kt] = Arow[kt * 4 + quad];
  float4v acc[8];
#pragma unroll
  for (int nt = 0; nt < 8; nt++) acc[nt] = (float4v)0.0f;
#pragma unroll
  for (int nt = 0; nt < 8; nt++) {
#pragma unroll
    for (int kt = 0; kt < 4; kt++) {
      uint4 b = Bl[((kt * 8 + nt) * 4 + quad) * 16 + m];
      acc[nt] = __builtin_amdgcn_mfma_f32_16x16x32_bf16(
          *(short8*)&a[kt], *(short8*)&b, acc[nt], 0, 0, 0);
    }
  }
  unsigned short* Dw = Dl + w * 2048;
#pragma unroll
  for (int r = 0; r < 4; r++) {
    float dv = dvs[w * 16 + quad * 4 + r];
#pragma unroll
    for (int nt = 0; nt < 8; nt++) {
      Dw[(quad * 4 + r) * 128 + nt * 16 + m] =
          (unsigned short)bf16_rn(acc[nt][r] * dv);
    }
  }
  __syncthreads();
  const uint4* Dw4 = (const uint4*)Dw;
#pragma unroll
  for (int p = 0; p < 4; p++) {
    int row = row0 + w * 16 + p * 4 + (lane >> 4);
    if (row < N) {
      ((uint4*)(Lb + (size_t)row * 128))[lane & 15] = Dw4[p * 64 + lane];
    }
  }
}

// SpMM over 128-dim bf16 rows (256B). 8 groups x 32 lanes; ONE node per group.
// Indices loaded 32-wide, shfl-broadcast, gathers dependency-free. fp32 acc.
// MODE 0: a = lrelu(dinv*(self+gather) + q*tw + b); write Aout (bf16); BN stats.
// MODE 1: same a, dot(a,Wout) group-reduced; pacc atomics run-aggregated per block.
template <int MODE>
__global__ __launch_bounds__(256, 8) void k_spmm(
    const unsigned* __restrict__ Lb, const int* __restrict__ offs,
    const int* __restrict__ cnt, const int* __restrict__ rows,
    const float* __restrict__ dinv, const float* __restrict__ qv,
    const float* __restrict__ tw, const float* __restrict__ bias,
    unsigned short* __restrict__ Aout, float* __restrict__ stats,
    const float* __restrict__ wout, const int* __restrict__ batch,
    float* __restrict__ pacc, int N) {
  const int t = threadIdx.x;
  const int g = t >> 5;
  const int q32 = t & 31;
  const uint2* __restrict__ L2p = (const uint2*)Lb;
  const float4 t4 = ((const float4*)tw)[q32];
  const float4 b4 = ((const float4*)bias)[q32];
  float4 wo4 = make_float4(0, 0, 0, 0);
  if (MODE == 1) wo4 = ((const float4*)wout)[q32];
  __shared__ float rs[128], rq[128];
  __shared__ float psum[8];
  __shared__ int pb[8];
  float4 ls = make_float4(0, 0, 0, 0), lq = make_float4(0, 0, 0, 0);
  if (MODE == 0) {
    if (t < 128) { rs[t] = 0.f; rq[t] = 0.f; }
    __syncthreads();
  } else {
    if (t < 8) pb[t] = -1;
    __syncthreads();
  }
  const int v = blockIdx.x * 8 + g;
  if (v < N) {
    const int st = offs[v];
    const int dg = cnt[v];
    float4 s0 = unpack_bf16x4(L2p[(size_t)v * 32 + q32]);
    float4 s1 = make_float4(0, 0, 0, 0), s2 = s1, s3 = s1;
    for (int b = 0; b < dg; b += 32) {
      int rem = dg - b;
      int idx = 0;
      if (q32 < rem) idx = rows[st + b + q32];
      int mm = rem < 32 ? rem : 32;
      int e = 0;
      for (; e + 8 <= mm; e += 8) {
        int r0 = __shfl(idx, e + 0, 32), r1 = __shfl(idx, e + 1, 32);
        int r2 = __shfl(idx, e + 2, 32), r3 = __shfl(idx, e + 3, 32);
        int r4 = __shfl(idx, e + 4, 32), r5 = __shfl(idx, e + 5, 32);
        int r6 = __shfl(idx, e + 6, 32), r7 = __shfl(idx, e + 7, 32);
        uint2 u0 = L2p[(size_t)r0 * 32 + q32];
        uint2 u1 = L2p[(size_t)r1 * 32 + q32];
        uint2 u2 = L2p[(size_t)r2 * 32 + q32];
        uint2 u3 = L2p[(size_t)r3 * 32 + q32];
        uint2 u4 = L2p[(size_t)r4 * 32 + q32];
        uint2 u5 = L2p[(size_t)r5 * 32 + q32];
        uint2 u6 = L2p[(size_t)r6 * 32 + q32];
        uint2 u7 = L2p[(size_t)r7 * 32 + q32];
        float4 g0 = unpack_bf16x4(u0); ADD4(s0, g0);
        float4 g1 = unpack_bf16x4(u1); ADD4(s1, g1);
        float4 g2 = unpack_bf16x4(u2); ADD4(s2, g2);
        float4 g3 = unpack_bf16x4(u3); ADD4(s3, g3);
        float4 g4 = unpack_bf16x4(u4); ADD4(s0, g4);
        float4 g5 = unpack_bf16x4(u5); ADD4(s1, g5);
        float4 g6 = unpack_bf16x4(u6); ADD4(s2, g6);
        float4 g7 = unpack_bf16x4(u7); ADD4(s3, g7);
      }
      for (; e + 4 <= mm; e += 4) {
        int r0 = __shfl(idx, e + 0, 32), r1 = __shfl(idx, e + 1, 32);
        int r2 = __shfl(idx, e + 2, 32), r3 = __shfl(idx, e + 3, 32);
        uint2 u0 = L2p[(size_t)r0 * 32 + q32];
        uint2 u1 = L2p[(size_t)r1 * 32 + q32];
        uint2 u2 = L2p[(size_t)r2 * 32 + q32];
        uint2 u3 = L2p[(size_t)r3 * 32 + q32];
        float4 g0 = unpack_bf16x4(u0); ADD4(s0, g0);
        float4 g1 = unpack_bf16x4(u1); ADD4(s1, g1);
        float4 g2 = unpack_bf16x4(u2); ADD4(s2, g2);
        float4 g3 = unpack_bf16x4(u3); ADD4(s3, g3);
      }
      for (; e < mm; e++) {
        int r = __shfl(idx, e, 32);
        float4 g0 = unpack_bf16x4(L2p[(size_t)r * 32 + q32]);
        ADD4(s0, g0);
      }
    }
    float4 acc;
    acc.x = (s0.x + s1.x) + (s2.x + s3.x);
    acc.y = (s0.y + s1.y) + (s2.y + s3.y);
    acc.z = (s0.z + s1.z) + (s2.z + s3.z);
    acc.w = (s0.w + s1.w) + (s2.w + s3.w);
    const float dv = dinv[v];
    const float qf = qv[v];
    float4 a;
    a.x = LRELU(dv * acc.x + qf * t4.x + b4.x);
    a.y = LRELU(dv * acc.y + qf * t4.y + b4.y);
    a.z = LRELU(dv * acc.z + qf * t4.z + b4.z);
    a.w = LRELU(dv * acc.w + qf * t4.w + b4.w);
    if (MODE == 0) {
      uint2 p;
      p.x = pack_bf16x2(a.x, a.y);
      p.y = pack_bf16x2(a.z, a.w);
      ((uint2*)Aout)[(size_t)v * 32 + q32] = p;
      ls.x += a.x; ls.y += a.y; ls.z += a.z; ls.w += a.w;
      lq.x += a.x * a.x; lq.y += a.y * a.y;
      lq.z += a.z * a.z; lq.w += a.w * a.w;
    } else {
      float s = a.x * wo4.x + a.y * wo4.y + a.z * wo4.z + a.w * wo4.w;
      s += __shfl_down(s, 16, 32);
      s += __shfl_down(s, 8, 32);
      s += __shfl_down(s, 4, 32);
      s += __shfl_down(s, 2, 32);
      s += __shfl_down(s, 1, 32);
      if (q32 == 0) {
        psum[g] = s;
        pb[g] = batch[v];
      }
    }
  }
  if (MODE == 0) {
    const int f0 = q32 * 4;
    atomicAdd(&rs[f0 + 0], ls.x); atomicAdd(&rs[f0 + 1], ls.y);
    atomicAdd(&rs[f0 + 2], ls.z); atomicAdd(&rs[f0 + 3], ls.w);
    atomicAdd(&rq[f0 + 0], lq.x); atomicAdd(&rq[f0 + 1], lq.y);
    atomicAdd(&rq[f0 + 2], lq.z); atomicAdd(&rq[f0 + 3], lq.w);
    __syncthreads();
    if (t < 128) {
      atomicAdd(&stats[t], rs[t]);
      atomicAdd(&stats[128 + t], rq[t]);
    }
  } else {
    __syncthreads();
    if (t < 8) {
      int b = pb[t];
      if (b >= 0 && (t == 0 || pb[t - 1] != b)) {
        float s = psum[t];
        for (int j = t + 1; j < 8 && pb[j] == b; j++) s += psum[j];
        atomicAdd(&pacc[b], s);
      }
    }
  }
}

// Fold BN affine into next layer's weights (parallel: 8 blocks x 16 W-rows).
// Emits bf16 Wb in MFMA B-frag order; tw accumulated atomically (pre-zeroed).
__global__ __launch_bounds__(128) void k_fold(const float* __restrict__ stats,
                                              const float* __restrict__ g,
                                              const float* __restrict__ be,
                                              const float* __restrict__ W,
                                              unsigned short* __restrict__ Wb,
                                              float* __restrict__ tw, float invN) {
  const int j = threadIdx.x;
  const int i0 = blockIdx.x * 16;
  const int nt = j >> 4;
  const int n = j & 15;
  float acc = 0.f;
#pragma unroll
  for (int ii = 0; ii < 16; ii++) {
    int i = i0 + ii;
    float m = stats[i] * invN;
    float var = stats[128 + i] * invN - m * m;
    float si = g[i] * rsqrtf(var + 1e-5f);
    float ti = be[i] - m * si;
    float w = W[i * 128 + j];
    acc += ti * w;
    int kt = i >> 5, quad = (i >> 3) & 3, jj = i & 7;
    Wb[((((kt * 8 + nt) * 4 + quad) * 16 + n) << 3) + jj] =
        (unsigned short)bf16_rn(si * w);
  }
  atomicAdd(&tw[j], acc);
}

// out[g] = pacc[g]/cnt(g) + bout; cnt(g) via binary search on SORTED batch.
__global__ __launch_bounds__(256) void k_out(const float* __restrict__ pacc,
                                             const int* __restrict__ batch,
                                             const float* __restrict__ bout,
                                             float* __restrict__ out,
                                             int N, int G) {
  int g = blockIdx.x * 256 + threadIdx.x;
  if (g >= G) return;
  int lo = 0, hi = N;
  while (lo < hi) { int mid = (lo + hi) >> 1; if (batch[mid] < g) lo = mid + 1; else hi = mid; }
  int a = lo;
  hi = N;
  while (lo < hi) { int mid = (lo + hi) >> 1; if (batch[mid] < g + 1) lo = mid + 1; else hi = mid; }
  float c = (float)(lo - a);
  out[g] = pacc[g] / fmaxf(c, 1.0f) + bout[0];
}

extern "C" void kernel_launch(void* const* d_in, const int* in_sizes, int n_in,
                              void* d_out, int out_size, void* d_ws, size_t ws_size,
                              hipStream_t stream) {
  const float* x    = (const float*)d_in[0];
  const int*   ei   = (const int*)d_in[1];
  const int*   batch= (const int*)d_in[2];
  const float* W0   = (const float*)d_in[3];
  const float* b0   = (const float*)d_in[4];
  const float* W1   = (const float*)d_in[5];
  const float* b1   = (const float*)d_in[6];
  const float* W2   = (const float*)d_in[7];
  const float* b2   = (const float*)d_in[8];
  const float* W3   = (const float*)d_in[9];
  const float* b3   = (const float*)d_in[10];
  const float* g1   = (const float*)d_in[11];
  const float* be1  = (const float*)d_in[12];
  const float* g2   = (const float*)d_in[13];
  const float* be2  = (const float*)d_in[14];
  const float* g3   = (const float*)d_in[15];
  const float* be3  = (const float*)d_in[16];
  const float* Wout = (const float*)d_in[17];
  const float* bout = (const float*)d_in[18];
  float* out = (float*)d_out;

  const int N = in_sizes[0] / 9;
  const int E = in_sizes[1] / 2;
  const int G = out_size;

  char* w = (char*)d_ws;
  auto alloc = [&](size_t bytes) -> void* {
    void* p = (void*)w;
    w += (bytes + 255) & ~(size_t)255;
    return p;
  };
  // ---- zeroed region (ONE memset) ----
  char* zbase = w;
  int*   cnt    = (int*)alloc((size_t)N * 4);
  float* pacc   = (float*)alloc((size_t)G * 4);
  float* stats  = (float*)alloc(3 * 256 * 4);
  float* tw3    = (float*)alloc(3 * 128 * 4);
  size_t zsize = (size_t)(w - zbase);
  // ---- non-zeroed ----
  int*   offs   = (int*)alloc((size_t)N * 4);
  int*   incl   = (int*)alloc((size_t)N * 4);
  int*   bsums  = (int*)alloc(512 * 4);
  int*   bpref  = (int*)alloc(512 * 4);
  float* dinv   = (float*)alloc((size_t)N * 4);
  float* q      = (float*)alloc((size_t)N * 4);
  int*   rank   = (int*)alloc((size_t)E * 4);
  int*   rows   = (int*)alloc((size_t)E * 4);
  unsigned short* Wb = (unsigned short*)alloc(128 * 128 * 2);  // bf16 B-frag layout
  unsigned* u   = (unsigned*)alloc((size_t)N * 12 * 2);        // bf16, 24B rows
  float* ax     = (float*)alloc((size_t)N * 12 * 4);
  unsigned* Lb  = (unsigned*)alloc((size_t)N * 128 * 2);       // bf16 rows, 256B
  unsigned short* Abuf = (unsigned short*)alloc((size_t)N * 128 * 2);  // bf16 acts

  hipMemsetAsync(zbase, 0, zsize, stream);

  const int eb  = (E + 255) / 256;
  const int nbN = (N + 255) / 256;  // also the scan block count (must be <= 512)
  const int sb  = (N + 15) / 16;    // spmm9 / gemm_in blocks
  const int sb8 = (N + 7) / 8;      // spmm blocks (1 node per 32-lane group)
  const int mb  = (N + 63) / 64;    // mfma gemm blocks
  const float invN = 1.0f / (float)N;
  float* twA = tw3;
  float* twB = tw3 + 128;
  float* twC = tw3 + 256;

  // --- graph preprocessing ---
  k_count<<<eb, 256, 0, stream>>>(ei, cnt, rank, E);
  k_scan1<<<nbN, 256, 0, stream>>>(cnt, incl, bsums, dinv, N);
  k_scan2<<<1, 512, 0, stream>>>(bsums, bpref, nbN);
  k_scan3_prep<<<nbN, 256, 0, stream>>>(incl, cnt, bpref, offs, x, dinv, u, N);
  k_csr<<<eb, 256, 0, stream>>>(ei, offs, rank, rows, E);

  // --- layer 1: aggregate 9-dim input first (A x) @ W0; also emits q ---
  k_spmm9<<<sb, 256, 0, stream>>>((const unsigned short*)u, offs, cnt, rows,
                                  dinv, ax, q, N);
  k_gemm_in<<<sb, 256, 0, stream>>>(ax, W0, b0, Abuf, stats, N);
  // --- layer 2 ---
  k_fold<<<8, 128, 0, stream>>>(stats, g1, be1, W1, Wb, twA, invN);
  k_gemm_mfma<<<mb, 256, 0, stream>>>(Abuf, (const uint4*)Wb, dinv, (unsigned short*)Lb, N);
  k_spmm<0><<<sb8, 256, 0, stream>>>(Lb, offs, cnt, rows, dinv, q, twA, b1,
                                     Abuf, stats + 256, nullptr, nullptr, nullptr, N);
  // --- layer 3 ---
  k_fold<<<8, 128, 0, stream>>>(stats + 256, g2, be2, W2, Wb, twB, invN);
  k_gemm_mfma<<<mb, 256, 0, stream>>>(Abuf, (const uint4*)Wb, dinv, (unsigned short*)Lb, N);
  k_spmm<0><<<sb8, 256, 0, stream>>>(Lb, offs, cnt, rows, dinv, q, twB, b2,
                                     Abuf, stats + 512, nullptr, nullptr, nullptr, N);
  // --- layer 4 (+ fused pool @ Wout) ---
  k_fold<<<8, 128, 0, stream>>>(stats + 512, g3, be3, W3, Wb, twC, invN);
  k_gemm_mfma<<<mb, 256, 0, stream>>>(Abuf, (const uint4*)Wb, dinv, (unsigned short*)Lb, N);
  k_spmm<1><<<sb8, 256, 0, stream>>>(Lb, offs, cnt, rows, dinv, q, twC, b3,
                                     nullptr, nullptr, Wout, batch, pacc, N);
  k_out<<<(G + 255) / 256, 256, 0, stream>>>(pacc, batch, bout, out, N, G);
}

// Round 10
// 866.370 us; speedup vs baseline: 1.3872x; 1.3872x over previous
//
#include <hip/hip_runtime.h>

// GCN forward: 4x [GEMM -> symmetric-normalized aggregation -> lrelu -> BN(folded)]
// then mean-pool per graph @ Wout.
//
// Key structure:
//  - CSR via counting sort, rank captured in count pass (atomicAdd return) ->
//    placement pass has NO atomics.
//  - Layer 1 commuted: A(x@W0) = (Ax)@W0; u bf16 24B rows (slot 9 = bf16(dinv) so
//    spmm9's lane 9 computes sd -> q for free).
//  - dinv folded into GEMM/gather epilogues; BN folded into next GEMM.
//  - k_spmm gather wall (R2-R8): per-edge ~43 cy fixed + ~14.5 cy/128B line,
//    bound by chip-level random-line service. R9 falsified the occupancy lever:
//    __launch_bounds__(256,8) forced VGPR 44->32 -> scratch spills (WRITE_SIZE
//    31->87MB), spmm 188->348us. REVERTED to R8 shape: 2 nodes/32-lane group,
//    default VGPR budget. Do NOT cap VGPRs on this kernel.
//  - cntG computed by binary search inside k_out (sorted batch).
//  - L bf16 (256B rows), Abuf bf16; 128x128 GEMMs on bf16 MFMA 16x16x32.
//  - Final layer fuses pool; per-block run-aggregated pacc atomics.

#define LRELU(z) ((z) > 0.f ? (z) : 0.01f * (z))
#define ADD4(d, s) \
  { d.x += s.x; d.y += s.y; d.z += s.z; d.w += s.w; }

typedef __attribute__((ext_vector_type(8))) short short8;
typedef __attribute__((ext_vector_type(4))) float float4v;

__device__ inline unsigned bf16_rn(float a) {
  unsigned u = __float_as_uint(a);
  return (u + 0x7FFFu + ((u >> 16) & 1u)) >> 16;
}

__device__ inline unsigned pack_bf16x2(float a, float b) {
  return bf16_rn(a) | (bf16_rn(b) << 16);
}

__device__ inline float bf16f(unsigned short s) {
  return __uint_as_float(((unsigned)s) << 16);
}

__device__ inline float4 unpack_bf16x4(uint2 u) {
  float4 r;
  r.x = __uint_as_float(u.x << 16);
  r.y = __uint_as_float(u.x & 0xffff0000u);
  r.z = __uint_as_float(u.y << 16);
  r.w = __uint_as_float(u.y & 0xffff0000u);
  return r;
}

// count pass: cnt[col]++ and record each edge's rank within its column.
__global__ __launch_bounds__(256) void k_count(const int* __restrict__ ei,
                                               int* __restrict__ cnt,
                                               int* __restrict__ rank, int E) {
  int i = blockIdx.x * 256 + threadIdx.x;
  if (i < E) rank[i] = atomicAdd(&cnt[ei[E + i]], 1);
}

// block-scan of cnt + dinv fused
__global__ __launch_bounds__(256) void k_scan1(const int* __restrict__ cnt,
                                               int* __restrict__ incl,
                                               int* __restrict__ bsums,
                                               float* __restrict__ dinv, int N) {
  __shared__ int s[256];
  int tid = threadIdx.x;
  int idx = blockIdx.x * 256 + tid;
  int v = (idx < N) ? cnt[idx] : 0;
  if (idx < N) dinv[idx] = rsqrtf((float)(v + 1));
  s[tid] = v;
  __syncthreads();
  for (int off = 1; off < 256; off <<= 1) {
    int t = (tid >= off) ? s[tid - off] : 0;
    __syncthreads();
    s[tid] += t;
    __syncthreads();
  }
  if (idx < N) incl[idx] = s[tid];
  if (tid == 255) bsums[blockIdx.x] = s[255];
}

// nb must be <= 512 (N <= 131072 here: nb = 391)
__global__ __launch_bounds__(512) void k_scan2(const int* __restrict__ bsums,
                                               int* __restrict__ bpref, int nb) {
  __shared__ int s[512];
  int tid = threadIdx.x;
  int v = (tid < nb) ? bsums[tid] : 0;
  s[tid] = v;
  __syncthreads();
  for (int off = 1; off < 512; off <<= 1) {
    int t = (tid >= off) ? s[tid - off] : 0;
    __syncthreads();
    s[tid] += t;
    __syncthreads();
  }
  bpref[tid] = s[tid] - v;  // exclusive prefix of block sums
}

// offs computation + u preparation fused: u[v][0:9] = bf16(x[v][0:9]*dinv[v]),
// slot 9 = bf16(dinv[v]), slots 10,11 = 0. 24B rows.
__global__ __launch_bounds__(256) void k_scan3_prep(
    const int* __restrict__ incl, const int* __restrict__ cnt,
    const int* __restrict__ bpref, int* __restrict__ offs,
    const float* __restrict__ x, const float* __restrict__ dinv,
    unsigned* __restrict__ u, int N) {
  int idx = blockIdx.x * 256 + threadIdx.x;
  if (idx >= N) return;
  offs[idx] = incl[idx] - cnt[idx] + bpref[blockIdx.x];
  float dv = dinv[idx];
  const float* xr = x + (size_t)idx * 9;
  unsigned p0 = pack_bf16x2(xr[0] * dv, xr[1] * dv);
  unsigned p1 = pack_bf16x2(xr[2] * dv, xr[3] * dv);
  unsigned p2 = pack_bf16x2(xr[4] * dv, xr[5] * dv);
  unsigned p3 = pack_bf16x2(xr[6] * dv, xr[7] * dv);
  unsigned p4 = pack_bf16x2(xr[8] * dv, dv);
  uint2* u2 = (uint2*)u;
  u2[(size_t)idx * 3 + 0] = make_uint2(p0, p1);
  u2[(size_t)idx * 3 + 1] = make_uint2(p2, p3);
  u2[(size_t)idx * 3 + 2] = make_uint2(p4, 0u);
}

// CSR placement: NO atomics (offs random read + rank from count pass).
__global__ __launch_bounds__(256) void k_csr(const int* __restrict__ ei,
                                             const int* __restrict__ offs,
                                             const int* __restrict__ rank,
                                             int* __restrict__ rows, int E) {
  int i = blockIdx.x * 256 + threadIdx.x;
  if (i < E) {
    int c = ei[E + i];
    rows[offs[c] + rank[i]] = ei[i];
  }
}

// ax[v] = dinv[v]*(u[v] + sum_in u[row]); lane 9 accumulates sum_in dinv[row]
// and emits q[v] = dinv*(dinv+sd). 16-lane group per node; coalesced 16-wide
// index load, shfl-broadcast, dependency-free 2B gathers (L2-resident source).
__global__ __launch_bounds__(256) void k_spmm9(
    const unsigned short* __restrict__ u, const int* __restrict__ offs,
    const int* __restrict__ cnt, const int* __restrict__ rows,
    const float* __restrict__ dinv, float* __restrict__ ax,
    float* __restrict__ q, int N) {
  const int t = threadIdx.x;
  const int g = t >> 4;
  const int f = t & 15;
  const int v = blockIdx.x * 16 + g;
  if (v >= N) return;
  const int st = offs[v];
  const int dg = cnt[v];
  const bool act = (f < 10);
  float a0 = (f < 9) ? bf16f(u[(size_t)v * 12 + f]) : 0.f;
  float a1 = 0.f, a2 = 0.f, a3 = 0.f;
  for (int b = 0; b < dg; b += 16) {
    int rem = dg - b;
    int idx = 0;
    if (f < rem) idx = rows[st + b + f];
    int mm = rem < 16 ? rem : 16;
    int e = 0;
    for (; e + 8 <= mm; e += 8) {
      int r0 = __shfl(idx, e + 0, 16), r1 = __shfl(idx, e + 1, 16);
      int r2 = __shfl(idx, e + 2, 16), r3 = __shfl(idx, e + 3, 16);
      int r4 = __shfl(idx, e + 4, 16), r5 = __shfl(idx, e + 5, 16);
      int r6 = __shfl(idx, e + 6, 16), r7 = __shfl(idx, e + 7, 16);
      float x0 = 0, x1 = 0, x2 = 0, x3 = 0, x4 = 0, x5 = 0, x6 = 0, x7 = 0;
      if (act) {
        x0 = bf16f(u[(size_t)r0 * 12 + f]); x1 = bf16f(u[(size_t)r1 * 12 + f]);
        x2 = bf16f(u[(size_t)r2 * 12 + f]); x3 = bf16f(u[(size_t)r3 * 12 + f]);
        x4 = bf16f(u[(size_t)r4 * 12 + f]); x5 = bf16f(u[(size_t)r5 * 12 + f]);
        x6 = bf16f(u[(size_t)r6 * 12 + f]); x7 = bf16f(u[(size_t)r7 * 12 + f]);
      }
      a0 += x0; a1 += x1; a2 += x2; a3 += x3;
      a0 += x4; a1 += x5; a2 += x6; a3 += x7;
    }
    for (; e + 4 <= mm; e += 4) {
      int r0 = __shfl(idx, e + 0, 16), r1 = __shfl(idx, e + 1, 16);
      int r2 = __shfl(idx, e + 2, 16), r3 = __shfl(idx, e + 3, 16);
      float x0 = 0, x1 = 0, x2 = 0, x3 = 0;
      if (act) {
        x0 = bf16f(u[(size_t)r0 * 12 + f]); x1 = bf16f(u[(size_t)r1 * 12 + f]);
        x2 = bf16f(u[(size_t)r2 * 12 + f]); x3 = bf16f(u[(size_t)r3 * 12 + f]);
      }
      a0 += x0; a1 += x1; a2 += x2; a3 += x3;
    }
    for (; e < mm; e++) {
      int r = __shfl(idx, e, 16);
      if (act) a0 += bf16f(u[(size_t)r * 12 + f]);
    }
  }
  float sum = (a0 + a1) + (a2 + a3);
  if (f < 9) {
    ax[(size_t)v * 12 + f] = sum * dinv[v];
  } else if (f == 9) {
    float dv = dinv[v];
    q[v] = dv * (dv + sum);
  }
}

// h1 = lrelu(ax[v][0:9] @ W0 + b0); writes Abuf (bf16); accumulates fp32 BN stats.
__global__ __launch_bounds__(256) void k_gemm_in(
    const float* __restrict__ ax, const float* __restrict__ W0,
    const float* __restrict__ b0, unsigned short* __restrict__ Abuf,
    float* __restrict__ stats, int N) {
  __shared__ float Wl[9 * 128];
  __shared__ float rs[128], rq[128];
  const int t = threadIdx.x;
  for (int i = t; i < 9 * 128; i += 256) Wl[i] = W0[i];
  if (t < 128) { rs[t] = 0.f; rq[t] = 0.f; }
  __syncthreads();
  const int col = t & 127;
  const int rsub = t >> 7;
  const int base = blockIdx.x * 16;
  const float bc = b0[col];
  float ls = 0.f, lq = 0.f;
  for (int it = 0; it < 8; it++) {
    int row = base + it * 2 + rsub;
    if (row < N) {
      const float* ar = ax + (size_t)row * 12;
      float acc = bc;
#pragma unroll
      for (int k = 0; k < 9; k++) acc += ar[k] * Wl[k * 128 + col];
      float a = LRELU(acc);
      Abuf[(size_t)row * 128 + col] = (unsigned short)bf16_rn(a);
      ls += a;
      lq += a * a;
    }
  }
  atomicAdd(&rs[col], ls);
  atomicAdd(&rq[col], lq);
  __syncthreads();
  if (t < 128) {
    atomicAdd(&stats[t], rs[t]);
    atomicAdd(&stats[128 + t], rq[t]);
  }
}

// bf16 MFMA GEMM: L[v][:] = bf16((A[v][:] @ Wf) * dinv[v]).
// Block: 64 rows, 4 waves x (16 rows x 128 cols). Wb pre-swizzled B-frag order.
__global__ __launch_bounds__(256) void k_gemm_mfma(
    const unsigned short* __restrict__ Ab, const uint4* __restrict__ Wb,
    const float* __restrict__ dinv, unsigned short* __restrict__ Lb, int N) {
  __shared__ uint4 Bl[2048];               // 32 KB: all B fragments
  __shared__ unsigned short Dl[4 * 2048];  // 16 KB: per-wave D staging
  __shared__ float dvs[64];
  const int t = threadIdx.x;
  const int row0 = blockIdx.x * 64;
#pragma unroll
  for (int i = 0; i < 8; i++) Bl[t + i * 256] = Wb[t + i * 256];
  if (t < 64) {
    int r = row0 + t;
    dvs[t] = (r < N) ? dinv[r] : 0.f;
  }
  __syncthreads();
  const int w = t >> 6;
  const int lane = t & 63;
  const int m = lane & 15;
  const int quad = lane >> 4;
  const int rowA = min(row0 + w * 16 + m, N - 1);
  const uint4* Arow = (const uint4*)(Ab + (size_t)rowA * 128);
  uint4 a[4];
#pragma unroll
  for (int kt = 0; kt < 4; kt++) a[kt] = Arow[kt * 4 + quad];
  float4v acc[8];
#pragma unroll
  for (int nt = 0; nt < 8; nt++) acc[nt] = (float4v)0.0f;
#pragma unroll
  for (int nt = 0; nt < 8; nt++) {
#pragma unroll
    for (int kt = 0; kt < 4; kt++) {
      uint4 b = Bl[((kt * 8 + nt) * 4 + quad) * 16 + m];
      acc[nt] = __builtin_amdgcn_mfma_f32_16x16x32_bf16(
          *(short8*)&a[kt], *(short8*)&b, acc[nt], 0, 0, 0);
    }
  }
  unsigned short* Dw = Dl + w * 2048;
#pragma unroll
  for (int r = 0; r < 4; r++) {
    float dv = dvs[w * 16 + quad * 4 + r];
#pragma unroll
    for (int nt = 0; nt < 8; nt++) {
      Dw[(quad * 4 + r) * 128 + nt * 16 + m] =
          (unsigned short)bf16_rn(acc[nt][r] * dv);
    }
  }
  __syncthreads();
  const uint4* Dw4 = (const uint4*)Dw;
#pragma unroll
  for (int p = 0; p < 4; p++) {
    int row = row0 + w * 16 + p * 4 + (lane >> 4);
    if (row < N) {
      ((uint4*)(Lb + (size_t)row * 128))[lane & 15] = Dw4[p * 64 + lane];
    }
  }
}

// SpMM over 128-dim bf16 rows (256B). 8 groups x 32 lanes; group owns 2 nodes
// sequentially (R8 shape — default VGPR budget, no min-waves bound).
// Indices loaded 32-wide, shfl-broadcast, gathers dependency-free. fp32 acc.
// MODE 0: a = lrelu(dinv*(self+gather) + q*tw + b); write Aout (bf16); BN stats.
// MODE 1: same a, dot(a,Wout) group-reduced; pacc atomics run-aggregated per block.
template <int MODE>
__global__ __launch_bounds__(256) void k_spmm(
    const unsigned* __restrict__ Lb, const int* __restrict__ offs,
    const int* __restrict__ cnt, const int* __restrict__ rows,
    const float* __restrict__ dinv, const float* __restrict__ qv,
    const float* __restrict__ tw, const float* __restrict__ bias,
    unsigned short* __restrict__ Aout, float* __restrict__ stats,
    const float* __restrict__ wout, const int* __restrict__ batch,
    float* __restrict__ pacc, int N) {
  const int t = threadIdx.x;
  const int g = t >> 5;
  const int q32 = t & 31;
  const uint2* __restrict__ L2p = (const uint2*)Lb;
  const float4 t4 = ((const float4*)tw)[q32];
  const float4 b4 = ((const float4*)bias)[q32];
  float4 wo4 = make_float4(0, 0, 0, 0);
  if (MODE == 1) wo4 = ((const float4*)wout)[q32];
  __shared__ float rs[128], rq[128];
  __shared__ float psum[16];
  __shared__ int pb[16];
  float4 ls = make_float4(0, 0, 0, 0), lq = make_float4(0, 0, 0, 0);
  if (MODE == 0) {
    if (t < 128) { rs[t] = 0.f; rq[t] = 0.f; }
    __syncthreads();
  } else {
    if (t < 16) pb[t] = -1;
    __syncthreads();
  }
  const int vbase = blockIdx.x * 16 + g * 2;
  for (int n = 0; n < 2; n++) {
    const int v = vbase + n;
    if (v >= N) break;
    const int st = offs[v];
    const int dg = cnt[v];
    float4 s0 = unpack_bf16x4(L2p[(size_t)v * 32 + q32]);
    float4 s1 = make_float4(0, 0, 0, 0), s2 = s1, s3 = s1;
    for (int b = 0; b < dg; b += 32) {
      int rem = dg - b;
      int idx = 0;
      if (q32 < rem) idx = rows[st + b + q32];
      int mm = rem < 32 ? rem : 32;
      int e = 0;
      for (; e + 8 <= mm; e += 8) {
        int r0 = __shfl(idx, e + 0, 32), r1 = __shfl(idx, e + 1, 32);
        int r2 = __shfl(idx, e + 2, 32), r3 = __shfl(idx, e + 3, 32);
        int r4 = __shfl(idx, e + 4, 32), r5 = __shfl(idx, e + 5, 32);
        int r6 = __shfl(idx, e + 6, 32), r7 = __shfl(idx, e + 7, 32);
        uint2 u0 = L2p[(size_t)r0 * 32 + q32];
        uint2 u1 = L2p[(size_t)r1 * 32 + q32];
        uint2 u2 = L2p[(size_t)r2 * 32 + q32];
        uint2 u3 = L2p[(size_t)r3 * 32 + q32];
        uint2 u4 = L2p[(size_t)r4 * 32 + q32];
        uint2 u5 = L2p[(size_t)r5 * 32 + q32];
        uint2 u6 = L2p[(size_t)r6 * 32 + q32];
        uint2 u7 = L2p[(size_t)r7 * 32 + q32];
        float4 g0 = unpack_bf16x4(u0); ADD4(s0, g0);
        float4 g1 = unpack_bf16x4(u1); ADD4(s1, g1);
        float4 g2 = unpack_bf16x4(u2); ADD4(s2, g2);
        float4 g3 = unpack_bf16x4(u3); ADD4(s3, g3);
        float4 g4 = unpack_bf16x4(u4); ADD4(s0, g4);
        float4 g5 = unpack_bf16x4(u5); ADD4(s1, g5);
        float4 g6 = unpack_bf16x4(u6); ADD4(s2, g6);
        float4 g7 = unpack_bf16x4(u7); ADD4(s3, g7);
      }
      for (; e + 4 <= mm; e += 4) {
        int r0 = __shfl(idx, e + 0, 32), r1 = __shfl(idx, e + 1, 32);
        int r2 = __shfl(idx, e + 2, 32), r3 = __shfl(idx, e + 3, 32);
        uint2 u0 = L2p[(size_t)r0 * 32 + q32];
        uint2 u1 = L2p[(size_t)r1 * 32 + q32];
        uint2 u2 = L2p[(size_t)r2 * 32 + q32];
        uint2 u3 = L2p[(size_t)r3 * 32 + q32];
        float4 g0 = unpack_bf16x4(u0); ADD4(s0, g0);
        float4 g1 = unpack_bf16x4(u1); ADD4(s1, g1);
        float4 g2 = unpack_bf16x4(u2); ADD4(s2, g2);
        float4 g3 = unpack_bf16x4(u3); ADD4(s3, g3);
      }
      for (; e < mm; e++) {
        int r = __shfl(idx, e, 32);
        float4 g0 = unpack_bf16x4(L2p[(size_t)r * 32 + q32]);
        ADD4(s0, g0);
      }
    }
    float4 acc;
    acc.x = (s0.x + s1.x) + (s2.x + s3.x);
    acc.y = (s0.y + s1.y) + (s2.y + s3.y);
    acc.z = (s0.z + s1.z) + (s2.z + s3.z);
    acc.w = (s0.w + s1.w) + (s2.w + s3.w);
    const float dv = dinv[v];
    const float qf = qv[v];
    float4 a;
    a.x = LRELU(dv * acc.x + qf * t4.x + b4.x);
    a.y = LRELU(dv * acc.y + qf * t4.y + b4.y);
    a.z = LRELU(dv * acc.z + qf * t4.z + b4.z);
    a.w = LRELU(dv * acc.w + qf * t4.w + b4.w);
    if (MODE == 0) {
      uint2 p;
      p.x = pack_bf16x2(a.x, a.y);
      p.y = pack_bf16x2(a.z, a.w);
      ((uint2*)Aout)[(size_t)v * 32 + q32] = p;
      ls.x += a.x; ls.y += a.y; ls.z += a.z; ls.w += a.w;
      lq.x += a.x * a.x; lq.y += a.y * a.y;
      lq.z += a.z * a.z; lq.w += a.w * a.w;
    } else {
      float s = a.x * wo4.x + a.y * wo4.y + a.z * wo4.z + a.w * wo4.w;
      s += __shfl_down(s, 16, 32);
      s += __shfl_down(s, 8, 32);
      s += __shfl_down(s, 4, 32);
      s += __shfl_down(s, 2, 32);
      s += __shfl_down(s, 1, 32);
      if (q32 == 0) {
        psum[g * 2 + n] = s;
        pb[g * 2 + n] = batch[v];
      }
    }
  }
  if (MODE == 0) {
    const int f0 = q32 * 4;
    atomicAdd(&rs[f0 + 0], ls.x); atomicAdd(&rs[f0 + 1], ls.y);
    atomicAdd(&rs[f0 + 2], ls.z); atomicAdd(&rs[f0 + 3], ls.w);
    atomicAdd(&rq[f0 + 0], lq.x); atomicAdd(&rq[f0 + 1], lq.y);
    atomicAdd(&rq[f0 + 2], lq.z); atomicAdd(&rq[f0 + 3], lq.w);
    __syncthreads();
    if (t < 128) {
      atomicAdd(&stats[t], rs[t]);
      atomicAdd(&stats[128 + t], rq[t]);
    }
  } else {
    __syncthreads();
    if (t < 16) {
      int b = pb[t];
      if (b >= 0 && (t == 0 || pb[t - 1] != b)) {
        float s = psum[t];
        for (int j = t + 1; j < 16 && pb[j] == b; j++) s += psum[j];
        atomicAdd(&pacc[b], s);
      }
    }
  }
}

// Fold BN affine into next layer's weights (parallel: 8 blocks x 16 W-rows).
// Emits bf16 Wb in MFMA B-frag order; tw accumulated atomically (pre-zeroed).
__global__ __launch_bounds__(128) void k_fold(const float* __restrict__ stats,
                                              const float* __restrict__ g,
                                              const float* __restrict__ be,
                                              const float* __restrict__ W,
                                              unsigned short* __restrict__ Wb,
                                              float* __restrict__ tw, float invN) {
  const int j = threadIdx.x;
  const int i0 = blockIdx.x * 16;
  const int nt = j >> 4;
  const int n = j & 15;
  float acc = 0.f;
#pragma unroll
  for (int ii = 0; ii < 16; ii++) {
    int i = i0 + ii;
    float m = stats[i] * invN;
    float var = stats[128 + i] * invN - m * m;
    float si = g[i] * rsqrtf(var + 1e-5f);
    float ti = be[i] - m * si;
    float w = W[i * 128 + j];
    acc += ti * w;
    int kt = i >> 5, quad = (i >> 3) & 3, jj = i & 7;
    Wb[((((kt * 8 + nt) * 4 + quad) * 16 + n) << 3) + jj] =
        (unsigned short)bf16_rn(si * w);
  }
  atomicAdd(&tw[j], acc);
}

// out[g] = pacc[g]/cnt(g) + bout; cnt(g) via binary search on SORTED batch.
__global__ __launch_bounds__(256) void k_out(const float* __restrict__ pacc,
                                             const int* __restrict__ batch,
                                             const float* __restrict__ bout,
                                             float* __restrict__ out,
                                             int N, int G) {
  int g = blockIdx.x * 256 + threadIdx.x;
  if (g >= G) return;
  int lo = 0, hi = N;
  while (lo < hi) { int mid = (lo + hi) >> 1; if (batch[mid] < g) lo = mid + 1; else hi = mid; }
  int a = lo;
  hi = N;
  while (lo < hi) { int mid = (lo + hi) >> 1; if (batch[mid] < g + 1) lo = mid + 1; else hi = mid; }
  float c = (float)(lo - a);
  out[g] = pacc[g] / fmaxf(c, 1.0f) + bout[0];
}

extern "C" void kernel_launch(void* const* d_in, const int* in_sizes, int n_in,
                              void* d_out, int out_size, void* d_ws, size_t ws_size,
                              hipStream_t stream) {
  const float* x    = (const float*)d_in[0];
  const int*   ei   = (const int*)d_in[1];
  const int*   batch= (const int*)d_in[2];
  const float* W0   = (const float*)d_in[3];
  const float* b0   = (const float*)d_in[4];
  const float* W1   = (const float*)d_in[5];
  const float* b1   = (const float*)d_in[6];
  const float* W2   = (const float*)d_in[7];
  const float* b2   = (const float*)d_in[8];
  const float* W3   = (const float*)d_in[9];
  const float* b3   = (const float*)d_in[10];
  const float* g1   = (const float*)d_in[11];
  const float* be1  = (const float*)d_in[12];
  const float* g2   = (const float*)d_in[13];
  const float* be2  = (const float*)d_in[14];
  const float* g3   = (const float*)d_in[15];
  const float* be3  = (const float*)d_in[16];
  const float* Wout = (const float*)d_in[17];
  const float* bout = (const float*)d_in[18];
  float* out = (float*)d_out;

  const int N = in_sizes[0] / 9;
  const int E = in_sizes[1] / 2;
  const int G = out_size;

  char* w = (char*)d_ws;
  auto alloc = [&](size_t bytes) -> void* {
    void* p = (void*)w;
    w += (bytes + 255) & ~(size_t)255;
    return p;
  };
  // ---- zeroed region (ONE memset) ----
  char* zbase = w;
  int*   cnt    = (int*)alloc((size_t)N * 4);
  float* pacc   = (float*)alloc((size_t)G * 4);
  float* stats  = (float*)alloc(3 * 256 * 4);
  float* tw3    = (float*)alloc(3 * 128 * 4);
  size_t zsize = (size_t)(w - zbase);
  // ---- non-zeroed ----
  int*   offs   = (int*)alloc((size_t)N * 4);
  int*   incl   = (int*)alloc((size_t)N * 4);
  int*   bsums  = (int*)alloc(512 * 4);
  int*   bpref  = (int*)alloc(512 * 4);
  float* dinv   = (float*)alloc((size_t)N * 4);
  float* q      = (float*)alloc((size_t)N * 4);
  int*   rank   = (int*)alloc((size_t)E * 4);
  int*   rows   = (int*)alloc((size_t)E * 4);
  unsigned short* Wb = (unsigned short*)alloc(128 * 128 * 2);  // bf16 B-frag layout
  unsigned* u   = (unsigned*)alloc((size_t)N * 12 * 2);        // bf16, 24B rows
  float* ax     = (float*)alloc((size_t)N * 12 * 4);
  unsigned* Lb  = (unsigned*)alloc((size_t)N * 128 * 2);       // bf16 rows, 256B
  unsigned short* Abuf = (unsigned short*)alloc((size_t)N * 128 * 2);  // bf16 acts

  hipMemsetAsync(zbase, 0, zsize, stream);

  const int eb  = (E + 255) / 256;
  const int nbN = (N + 255) / 256;  // also the scan block count (must be <= 512)
  const int sb  = (N + 15) / 16;    // spmm / spmm9 / gemm_in blocks
  const int mb  = (N + 63) / 64;    // mfma gemm blocks
  const float invN = 1.0f / (float)N;
  float* twA = tw3;
  float* twB = tw3 + 128;
  float* twC = tw3 + 256;

  // --- graph preprocessing ---
  k_count<<<eb, 256, 0, stream>>>(ei, cnt, rank, E);
  k_scan1<<<nbN, 256, 0, stream>>>(cnt, incl, bsums, dinv, N);
  k_scan2<<<1, 512, 0, stream>>>(bsums, bpref, nbN);
  k_scan3_prep<<<nbN, 256, 0, stream>>>(incl, cnt, bpref, offs, x, dinv, u, N);
  k_csr<<<eb, 256, 0, stream>>>(ei, offs, rank, rows, E);

  // --- layer 1: aggregate 9-dim input first (A x) @ W0; also emits q ---
  k_spmm9<<<sb, 256, 0, stream>>>((const unsigned short*)u, offs, cnt, rows,
                                  dinv, ax, q, N);
  k_gemm_in<<<sb, 256, 0, stream>>>(ax, W0, b0, Abuf, stats, N);
  // --- layer 2 ---
  k_fold<<<8, 128, 0, stream>>>(stats, g1, be1, W1, Wb, twA, invN);
  k_gemm_mfma<<<mb, 256, 0, stream>>>(Abuf, (const uint4*)Wb, dinv, (unsigned short*)Lb, N);
  k_spmm<0><<<sb, 256, 0, stream>>>(Lb, offs, cnt, rows, dinv, q, twA, b1,
                                    Abuf, stats + 256, nullptr, nullptr, nullptr, N);
  // --- layer 3 ---
  k_fold<<<8, 128, 0, stream>>>(stats + 256, g2, be2, W2, Wb, twB, invN);
  k_gemm_mfma<<<mb, 256, 0, stream>>>(Abuf, (const uint4*)Wb, dinv, (unsigned short*)Lb, N);
  k_spmm<0><<<sb, 256, 0, stream>>>(Lb, offs, cnt, rows, dinv, q, twB, b2,
                                    Abuf, stats + 512, nullptr, nullptr, nullptr, N);
  // --- layer 4 (+ fused pool @ Wout) ---
  k_fold<<<8, 128, 0, stream>>>(stats + 512, g3, be3, W3, Wb, twC, invN);
  k_gemm_mfma<<<mb, 256, 0, stream>>>(Abuf, (const uint4*)Wb, dinv, (unsigned short*)Lb, N);
  k_spmm<1><<<sb, 256, 0, stream>>>(Lb, offs, cnt, rows, dinv, q, twC, b3,
                                    nullptr, nullptr, Wout, batch, pacc, N);
  k_out<<<(G + 255) / 256, 256, 0, stream>>>(pacc, batch, bout, out, N, G);
}